// Round 14
// baseline (827.274 us; speedup 1.0000x reference)
//
#include <hip/hip_runtime.h>
#include <hip/hip_cooperative_groups.h>

namespace cg = cooperative_groups;

// ---------------------------------------------------------------------------
// GCN: out = A_norm * relu(A_norm * X * W1 + b1) * W2 + b2
// A_norm = D^-1/2 (A + I) D^-1/2, built from 1.6M random edges + self loops.
//
// Round-14: launch-overhead endgame. Accounting shows ~13-15us per graph
// node; kernel bodies sum to ~115us but totals are ~240us. Fusion-by-barrier
// (k_agg_mm) is disproven twice (R10: 89us, R13: 97us vs 60us split -- block
// barrier holds CU slots hostage to the slowest wave). Instead: ONE
// cooperative kernel (k_all) runs all 8 phases with grid.sync() between,
// using the UNCHANGED proven phase bodies (R11's kernels, grid-strided).
// 22.5KB shared LDS pool -> 7 blocks/CU; grid from occupancy API. If the
// cooperative launch is rejected (e.g. by graph capture), fall back to
// R11's proven 8-launch chain in the same call (identical math).
// NOTE (round-8): LDS *float* atomics as accumulation substrate are ~25x too
// slow. Int LDS atomics at ~3M scale are fine.
// ---------------------------------------------------------------------------

#define EPB_LOG 12
#define EPB (1 << EPB_LOG)     // 4096 edges per partition chunk
#define BW_LOG 7
#define BW (1 << BW_LOG)       // 128 dst nodes per bucket
#define MAXBUCK 512            // fast path: n <= 65536
#define SCAN_TILE 2048

typedef __attribute__((ext_vector_type(8))) short bf16x8;
typedef __attribute__((ext_vector_type(4))) float f32x4;

__device__ inline unsigned short f2bf(float f) {
    unsigned int b = __float_as_uint(f);
    unsigned int r = b + 0x7FFFu + ((b >> 16) & 1u);   // round-to-nearest-even
    return (unsigned short)(r >> 16);
}
__device__ inline float bf_lo(unsigned int u) { return __uint_as_float(u << 16); }
__device__ inline float bf_hi(unsigned int u) { return __uint_as_float(u & 0xFFFF0000u); }

// Self-detect int64-vs-int32 edge storage from the first 64 odd words.
__device__ inline int detect_stride(const int* edges, int t, int* sh) {
    if (t < 64) {
        int v = edges[2 * t + 1];
        unsigned long long bb = __ballot(v != 0);
        if (t == 0) *sh = bb ? 1 : 2;
    }
    __syncthreads();
    return *sh;
}

// ---------------- cooperative mega-kernel (fast path) ----------------------

__global__ __launch_bounds__(256) void k_all(
        const int* __restrict__ edges, const float* __restrict__ x,
        const float* __restrict__ W1, const float* __restrict__ b1,
        const float* __restrict__ W2, const float* __restrict__ b2,
        float* __restrict__ out, unsigned short* __restrict__ w1t,
        int* __restrict__ btot_raw, int* __restrict__ btot,
        int* __restrict__ curg, unsigned int* __restrict__ part,
        int* __restrict__ csr_src, unsigned short* __restrict__ xs,
        int* __restrict__ rs, float* __restrict__ dis,
        float* __restrict__ svs, unsigned short* __restrict__ aggh,
        int n, long long E, int nsb, int nbuck) {
    cg::grid_group grid = cg::this_grid();
    __shared__ unsigned int stage[EPB];   // 16 KB
    __shared__ int bins[MAXBUCK];         // 2 KB  (also c128 in build)
    __shared__ int lcur[MAXBUCK];         // 2 KB
    __shared__ int gbase[MAXBUCK];        // 2 KB  (also dld floats in build)
    __shared__ int ws4[4];
    __shared__ int sh;
    int t = threadIdx.x;
    int B = blockIdx.x, NB = gridDim.x;
    int lane = t & 63, w = t >> 6;
    int stride = detect_stride(edges, t, &sh);

    // ---- phase 0: zero btot_raw; w1t = bf16(W1^T) ----
    for (int i = B * 256 + t; i < nbuck; i += NB * 256) btot_raw[i] = 0;
    for (int i = B * 256 + t; i < 256 * 128; i += NB * 256) {
        int row = i >> 7, k = i & 127;
        w1t[i] = f2bf(W1[k * 256 + row]);
    }
    grid.sync();

    // ---- phase 1: per-superblock bucket hist -> global atomic flush ----
    for (int sb = B; sb < nsb; sb += NB) {
        for (int i = t; i < nbuck; i += 256) bins[i] = 0;
        __syncthreads();
        long long base = (long long)sb << EPB_LOG;
        long long rem = E - base;
        int nE = (rem < (long long)EPB) ? (int)rem : EPB;
        for (int i = t; i < nE; i += 256) {
            int d = edges[(E + base + i) * stride];
            atomicAdd(&bins[d >> BW_LOG], 1);
        }
        __syncthreads();
        for (int i = t; i < nbuck; i += 256)
            if (bins[i]) atomicAdd(&btot_raw[i], bins[i]);
        __syncthreads();
    }
    grid.sync();

    // ---- phase 2: exclusive scan of bucket totals (block 0) ----
    if (B == 0) {
        int c4 = (nbuck + 255) >> 8;     // <=2
        int lo = t * c4;
        int hi = lo + c4; if (hi > nbuck) hi = nbuck;
        if (lo > nbuck) lo = nbuck;
        int vals[2];
        int local = 0;
        for (int i = lo; i < hi; ++i) { vals[i - lo] = btot_raw[i]; local += vals[i - lo]; }
        int inc = local;
        for (int off = 1; off < 64; off <<= 1) {
            int u = __shfl_up(inc, off, 64);
            if (lane >= off) inc += u;
        }
        if (lane == 63) ws4[w] = inc;
        __syncthreads();
        int woff = 0;
        for (int i = 0; i < w; ++i) woff += ws4[i];
        int ex = woff + inc - local;
        for (int i = lo; i < hi; ++i) {
            btot[i] = ex; curg[i] = ex;
            ex += vals[i - lo];
        }
    }
    grid.sync();

    // ---- phase 3: partition into bucket-contiguous packed (src<<16|dst) ----
    for (int sb = B; sb < nsb; sb += NB) {
        for (int i = t; i < nbuck; i += 256) bins[i] = 0;
        __syncthreads();
        long long base = (long long)sb << EPB_LOG;
        long long rem = E - base;
        int nE = (rem < (long long)EPB) ? (int)rem : EPB;
        for (int i = t; i < nE; i += 256) {
            int d = edges[(E + base + i) * stride];
            atomicAdd(&bins[d >> BW_LOG], 1);
        }
        __syncthreads();
        int c4 = (nbuck + 255) >> 8;
        int lo = t * c4;
        int hi = lo + c4; if (hi > nbuck) hi = nbuck;
        if (lo > nbuck) lo = nbuck;
        int vals[2];
        int local = 0;
        for (int i = lo; i < hi; ++i) { vals[i - lo] = bins[i]; local += vals[i - lo]; }
        for (int i = t; i < nbuck; i += 256) {
            int c = bins[i];
            gbase[i] = c ? atomicAdd(&curg[i], c) : 0;
        }
        __syncthreads();
        int inc = local;
        for (int off = 1; off < 64; off <<= 1) {
            int u = __shfl_up(inc, off, 64);
            if (lane >= off) inc += u;
        }
        if (lane == 63) ws4[w] = inc;
        __syncthreads();
        int woff = 0;
        for (int i = 0; i < w; ++i) woff += ws4[i];
        int ex = woff + inc - local;
        for (int i = lo; i < hi; ++i) {
            bins[i] = ex;
            lcur[i] = ex;
            ex += vals[i - lo];
        }
        __syncthreads();
        for (int i = t; i < nE; i += 256) {
            int s = edges[(base + i) * stride];
            int d = edges[(E + base + i) * stride];
            int bk = d >> BW_LOG;
            int p = atomicAdd(&lcur[bk], 1);
            stage[p] = ((unsigned int)s << 16) | (unsigned int)d;
        }
        __syncthreads();
        for (int i = t; i < nE; i += 256) {
            unsigned int pk = stage[i];
            int bk = (int)(pk & 0xFFFFu) >> BW_LOG;
            part[gbase[bk] + (i - bins[bk])] = pk;
        }
        __syncthreads();
    }
    grid.sync();

    // ---- phase 4: per-bucket deg->dis+row_start, csr ranks, xs conversion ----
    if (B == 0 && t == 0) rs[n] = (int)E;   // CSR sentinel
    for (int b = B; b < nbuck; b += NB) {
        int* c128 = bins;
        float* dld = (float*)gbase;
        if (t < BW) c128[t] = 0;
        __syncthreads();
        int start = btot[b];
        int endp = (b + 1 < nbuck) ? btot[b + 1] : (int)E;
        for (int i = start + t; i < endp; i += 256)
            atomicAdd(&c128[part[i] & (BW - 1)], 1);
        __syncthreads();
        int deg = (t < BW) ? c128[t] : 0;
        int inc = deg;
        for (int off = 1; off < 64; off <<= 1) {
            int u = __shfl_up(inc, off, 64);
            if (lane >= off) inc += u;
        }
        if (t < BW && lane == 63) ws4[w] = inc;
        __syncthreads();
        if (t < BW) {
            int ex = inc - deg + ((w == 1) ? ws4[0] : 0);
            lcur[t] = ex;
            int d = (b << BW_LOG) + t;
            if (d < n) {
                rs[d] = start + ex;
                float dv = rsqrtf((float)deg + 1.0f);   // +1 = self loop
                dis[d] = dv;
                dld[t] = dv;
            }
        }
        __syncthreads();
        for (int i = start + t; i < endp; i += 256) {
            unsigned int pk = part[i];
            int r = atomicAdd(&lcur[pk & (BW - 1)], 1);
            csr_src[start + r] = (int)(pk >> 16);
        }
        int d0 = b << BW_LOG;
        for (int idx = t; idx < BW * 32; idx += 256) {
            int node = d0 + (idx >> 5);
            if (node >= n) break;
            float dv = dld[idx >> 5];
            float4 v = ((const float4*)x)[(size_t)node * 32 + (idx & 31)];
            ushort4 o;
            o.x = f2bf(v.x * dv); o.y = f2bf(v.y * dv);
            o.z = f2bf(v.z * dv); o.w = f2bf(v.w * dv);
            ((ushort4*)xs)[(size_t)node * 32 + (idx & 31)] = o;
        }
        __syncthreads();
    }
    grid.sync();

    // ---- phase 5: aggregate (wave per node, 8-edge unroll) ----
    {
        const unsigned int* xsu = (const unsigned int*)xs;
        for (int node = B * 4 + w; node < n; node += NB * 4) {
            int start = rs[node], end = rs[node + 1];
            unsigned int self = xsu[((size_t)node << 6) + lane];
            float a0 = bf_lo(self), a1 = bf_hi(self);
            int e = start;
            for (; e + 7 < end; e += 8) {
                int s0 = csr_src[e],     s1 = csr_src[e + 1];
                int s2 = csr_src[e + 2], s3 = csr_src[e + 3];
                int s4 = csr_src[e + 4], s5 = csr_src[e + 5];
                int s6 = csr_src[e + 6], s7 = csr_src[e + 7];
                unsigned int v0 = xsu[((size_t)s0 << 6) + lane];
                unsigned int v1 = xsu[((size_t)s1 << 6) + lane];
                unsigned int v2 = xsu[((size_t)s2 << 6) + lane];
                unsigned int v3 = xsu[((size_t)s3 << 6) + lane];
                unsigned int v4 = xsu[((size_t)s4 << 6) + lane];
                unsigned int v5 = xsu[((size_t)s5 << 6) + lane];
                unsigned int v6 = xsu[((size_t)s6 << 6) + lane];
                unsigned int v7 = xsu[((size_t)s7 << 6) + lane];
                a0 += bf_lo(v0); a1 += bf_hi(v0);
                a0 += bf_lo(v1); a1 += bf_hi(v1);
                a0 += bf_lo(v2); a1 += bf_hi(v2);
                a0 += bf_lo(v3); a1 += bf_hi(v3);
                a0 += bf_lo(v4); a1 += bf_hi(v4);
                a0 += bf_lo(v5); a1 += bf_hi(v5);
                a0 += bf_lo(v6); a1 += bf_hi(v6);
                a0 += bf_lo(v7); a1 += bf_hi(v7);
            }
            for (; e < end; ++e) {
                int s0 = csr_src[e];
                unsigned int v0 = xsu[((size_t)s0 << 6) + lane];
                a0 += bf_lo(v0); a1 += bf_hi(v0);
            }
            float dn = dis[node];
            unsigned int pack = (unsigned int)f2bf(a0 * dn)
                              | ((unsigned int)f2bf(a1 * dn) << 16);
            ((unsigned int*)aggh)[((size_t)node << 6) + lane] = pack;
        }
    }
    grid.sync();

    // ---- phase 6: MFMA mm, svs = dis * (relu(agg@W1+b1)@W2) ----
    {
        int m = lane & 15, quad = lane >> 4;
        int ng = (n + 63) >> 6;
        for (int g = B; g < ng; g += NB) {
            int node0 = g * 64 + w * 16;
            bf16x8 afrag[4];
            const unsigned short* arow = aggh + (size_t)(node0 + m) * 128 + quad * 8;
#pragma unroll
            for (int ks = 0; ks < 4; ++ks)
                afrag[ks] = *(const bf16x8*)(arow + ks * 32);
            float p0 = 0.f, p1 = 0.f, p2 = 0.f, p3 = 0.f;
#pragma unroll 1
            for (int tt = 0; tt < 16; ++tt) {
                const unsigned short* brow = w1t + (size_t)(tt * 16 + m) * 128 + quad * 8;
                f32x4 acc = {0.f, 0.f, 0.f, 0.f};
#pragma unroll
                for (int ks = 0; ks < 4; ++ks) {
                    bf16x8 bfrag = *(const bf16x8*)(brow + ks * 32);
                    acc = __builtin_amdgcn_mfma_f32_16x16x32_bf16(afrag[ks], bfrag, acc, 0, 0, 0);
                }
                int col = tt * 16 + m;
                float bb = b1[col], w2 = W2[col];
                float h0 = acc[0] + bb, h1 = acc[1] + bb, h2 = acc[2] + bb, h3 = acc[3] + bb;
                p0 += (h0 > 0.f ? h0 : 0.f) * w2;
                p1 += (h1 > 0.f ? h1 : 0.f) * w2;
                p2 += (h2 > 0.f ? h2 : 0.f) * w2;
                p3 += (h3 > 0.f ? h3 : 0.f) * w2;
            }
#pragma unroll
            for (int off = 1; off < 16; off <<= 1) {
                p0 += __shfl_xor(p0, off, 64);
                p1 += __shfl_xor(p1, off, 64);
                p2 += __shfl_xor(p2, off, 64);
                p3 += __shfl_xor(p3, off, 64);
            }
            if (m == 0) {
                int nb = node0 + quad * 4;
                if (nb + 0 < n) svs[nb + 0] = p0 * dis[nb + 0];
                if (nb + 1 < n) svs[nb + 1] = p1 * dis[nb + 1];
                if (nb + 2 < n) svs[nb + 2] = p2 * dis[nb + 2];
                if (nb + 3 < n) svs[nb + 3] = p3 * dis[nb + 3];
            }
        }
    }
    grid.sync();

    // ---- phase 7: out[i] = b2 + dn_i * (sum_e svs[src_e] + svs[i]) ----
    for (int node = B * 4 + w; node < n; node += NB * 4) {
        int start = rs[node], end = rs[node + 1];
        float acc = 0.f;
        for (int e = start + lane; e < end; e += 64)
            acc += svs[csr_src[e]];
        for (int off = 32; off; off >>= 1) acc += __shfl_down(acc, off, 64);
        if (lane == 0)
            out[node] = dis[node] * (acc + svs[node]) + b2[0];
    }
}

// ---------------- R11 fast chain (fallback if cooperative launch fails) ----

__global__ __launch_bounds__(256) void k_count(
        const int* __restrict__ edges, const float* __restrict__ W1,
        unsigned short* __restrict__ w1t, int* __restrict__ btot_raw,
        long long E, int nbuck, int nsb) {
    int b = blockIdx.x, t = threadIdx.x;
    if (b >= nsb) {
        int row = (b - nsb) * 2 + (t >> 7);
        int k = t & 127;
        w1t[row * 128 + k] = f2bf(W1[k * 256 + row]);
        return;
    }
    __shared__ int bins[MAXBUCK];
    __shared__ int sh;
    for (int i = t; i < nbuck; i += 256) bins[i] = 0;
    int stride = detect_stride(edges, t, &sh);
    long long base = (long long)b << EPB_LOG;
    long long rem = E - base;
    int nE = (rem < (long long)EPB) ? (int)rem : EPB;
    for (int i = t; i < nE; i += 256) {
        int d = edges[(E + base + i) * stride];
        atomicAdd(&bins[d >> BW_LOG], 1);
    }
    __syncthreads();
    for (int i = t; i < nbuck; i += 256)
        if (bins[i]) atomicAdd(&btot_raw[i], bins[i]);
}

__global__ __launch_bounds__(256) void k_btot_scan(
        const int* __restrict__ btot_raw, int* __restrict__ btot,
        int* __restrict__ curg, int nbuck) {
    __shared__ int ws4[4];
    int t = threadIdx.x;
    int c4 = (nbuck + 255) >> 8;
    int lo = t * c4;
    int hi = lo + c4; if (hi > nbuck) hi = nbuck;
    if (lo > nbuck) lo = nbuck;
    int vals[2];
    int local = 0;
    for (int i = lo; i < hi; ++i) { vals[i - lo] = btot_raw[i]; local += vals[i - lo]; }
    int lane = t & 63, w = t >> 6;
    int inc = local;
    for (int off = 1; off < 64; off <<= 1) {
        int u = __shfl_up(inc, off, 64);
        if (lane >= off) inc += u;
    }
    if (lane == 63) ws4[w] = inc;
    __syncthreads();
    int woff = 0;
    for (int i = 0; i < w; ++i) woff += ws4[i];
    int ex = woff + inc - local;
    for (int i = lo; i < hi; ++i) {
        btot[i] = ex; curg[i] = ex;
        ex += vals[i - lo];
    }
}

__global__ __launch_bounds__(256) void k_partition(
        const int* __restrict__ edges, int* __restrict__ curg,
        unsigned int* __restrict__ part, long long E, int nbuck) {
    __shared__ unsigned int stage[EPB];
    __shared__ int bins[MAXBUCK];
    __shared__ int lcur[MAXBUCK];
    __shared__ int gbase[MAXBUCK];
    __shared__ int ws4[4];
    __shared__ int sh;
    int sb = blockIdx.x, t = threadIdx.x;
    for (int i = t; i < nbuck; i += 256) bins[i] = 0;
    int stride = detect_stride(edges, t, &sh);
    long long base = (long long)sb << EPB_LOG;
    long long rem = E - base;
    int nE = (rem < (long long)EPB) ? (int)rem : EPB;
    for (int i = t; i < nE; i += 256) {
        int d = edges[(E + base + i) * stride];
        atomicAdd(&bins[d >> BW_LOG], 1);
    }
    __syncthreads();
    int c4 = (nbuck + 255) >> 8;
    int lo = t * c4;
    int hi = lo + c4; if (hi > nbuck) hi = nbuck;
    if (lo > nbuck) lo = nbuck;
    int vals[2];
    int local = 0;
    for (int i = lo; i < hi; ++i) { vals[i - lo] = bins[i]; local += vals[i - lo]; }
    for (int i = t; i < nbuck; i += 256) {
        int c = bins[i];
        gbase[i] = c ? atomicAdd(&curg[i], c) : 0;
    }
    __syncthreads();
    int lane = t & 63, w = t >> 6;
    int inc = local;
    for (int off = 1; off < 64; off <<= 1) {
        int u = __shfl_up(inc, off, 64);
        if (lane >= off) inc += u;
    }
    if (lane == 63) ws4[w] = inc;
    __syncthreads();
    int woff = 0;
    for (int i = 0; i < w; ++i) woff += ws4[i];
    int ex = woff + inc - local;
    for (int i = lo; i < hi; ++i) {
        bins[i] = ex;
        lcur[i] = ex;
        ex += vals[i - lo];
    }
    __syncthreads();
    for (int i = t; i < nE; i += 256) {
        int s = edges[(base + i) * stride];
        int d = edges[(E + base + i) * stride];
        int bk = d >> BW_LOG;
        int p = atomicAdd(&lcur[bk], 1);
        stage[p] = ((unsigned int)s << 16) | (unsigned int)d;
    }
    __syncthreads();
    for (int i = t; i < nE; i += 256) {
        unsigned int pk = stage[i];
        int bk = (int)(pk & 0xFFFFu) >> BW_LOG;
        part[gbase[bk] + (i - bins[bk])] = pk;
    }
}

__global__ __launch_bounds__(256) void k_build_csr(
        const unsigned int* __restrict__ part, const int* __restrict__ btot,
        const float* __restrict__ x, int* __restrict__ row_start,
        float* __restrict__ dis, int* __restrict__ csr_src,
        unsigned short* __restrict__ xs, int nbuck, int n, long long E) {
    __shared__ int c128[BW];
    __shared__ int lcur[BW];
    __shared__ float dld[BW];
    __shared__ int ws2[2];
    int b = blockIdx.x, t = threadIdx.x;
    if (t < BW) c128[t] = 0;
    __syncthreads();
    int start = btot[b];
    int endp = (b + 1 < nbuck) ? btot[b + 1] : (int)E;
    for (int i = start + t; i < endp; i += 256)
        atomicAdd(&c128[part[i] & (BW - 1)], 1);
    __syncthreads();
    int lane = t & 63, w = t >> 6;
    int deg = (t < BW) ? c128[t] : 0;
    int inc = deg;
    for (int off = 1; off < 64; off <<= 1) {
        int u = __shfl_up(inc, off, 64);
        if (lane >= off) inc += u;
    }
    if (t < BW && lane == 63) ws2[w] = inc;
    __syncthreads();
    if (t < BW) {
        int ex = inc - deg + ((w == 1) ? ws2[0] : 0);
        lcur[t] = ex;
        int d = (b << BW_LOG) + t;
        if (d < n) {
            row_start[d] = start + ex;
            float dv = rsqrtf((float)deg + 1.0f);
            dis[d] = dv;
            dld[t] = dv;
        }
    }
    if (b == nbuck - 1 && t == 0) row_start[n] = (int)E;
    __syncthreads();
    for (int i = start + t; i < endp; i += 256) {
        unsigned int pk = part[i];
        int r = atomicAdd(&lcur[pk & (BW - 1)], 1);
        csr_src[start + r] = (int)(pk >> 16);
    }
    int d0 = b << BW_LOG;
    for (int idx = t; idx < BW * 32; idx += 256) {
        int node = d0 + (idx >> 5);
        if (node >= n) break;
        float dv = dld[idx >> 5];
        float4 v = ((const float4*)x)[(size_t)node * 32 + (idx & 31)];
        ushort4 o;
        o.x = f2bf(v.x * dv); o.y = f2bf(v.y * dv);
        o.z = f2bf(v.z * dv); o.w = f2bf(v.w * dv);
        ((ushort4*)xs)[(size_t)node * 32 + (idx & 31)] = o;
    }
}

__global__ __launch_bounds__(256) void k_agg(
        const unsigned short* __restrict__ xs, const int* __restrict__ csr_src,
        const int* __restrict__ row_start, const float* __restrict__ dis,
        unsigned short* __restrict__ aggh, int n) {
    int wid  = (blockIdx.x * blockDim.x + threadIdx.x) >> 6;
    int lane = threadIdx.x & 63;
    if (wid >= n) return;
    int start = row_start[wid], end = row_start[wid + 1];
    const unsigned int* xsu = (const unsigned int*)xs;
    unsigned int self = xsu[((size_t)wid << 6) + lane];
    float a0 = bf_lo(self), a1 = bf_hi(self);
    int e = start;
    for (; e + 7 < end; e += 8) {
        int s0 = csr_src[e],     s1 = csr_src[e + 1];
        int s2 = csr_src[e + 2], s3 = csr_src[e + 3];
        int s4 = csr_src[e + 4], s5 = csr_src[e + 5];
        int s6 = csr_src[e + 6], s7 = csr_src[e + 7];
        unsigned int v0 = xsu[((size_t)s0 << 6) + lane];
        unsigned int v1 = xsu[((size_t)s1 << 6) + lane];
        unsigned int v2 = xsu[((size_t)s2 << 6) + lane];
        unsigned int v3 = xsu[((size_t)s3 << 6) + lane];
        unsigned int v4 = xsu[((size_t)s4 << 6) + lane];
        unsigned int v5 = xsu[((size_t)s5 << 6) + lane];
        unsigned int v6 = xsu[((size_t)s6 << 6) + lane];
        unsigned int v7 = xsu[((size_t)s7 << 6) + lane];
        a0 += bf_lo(v0); a1 += bf_hi(v0);
        a0 += bf_lo(v1); a1 += bf_hi(v1);
        a0 += bf_lo(v2); a1 += bf_hi(v2);
        a0 += bf_lo(v3); a1 += bf_hi(v3);
        a0 += bf_lo(v4); a1 += bf_hi(v4);
        a0 += bf_lo(v5); a1 += bf_hi(v5);
        a0 += bf_lo(v6); a1 += bf_hi(v6);
        a0 += bf_lo(v7); a1 += bf_hi(v7);
    }
    for (; e < end; ++e) {
        int s0 = csr_src[e];
        unsigned int v0 = xsu[((size_t)s0 << 6) + lane];
        a0 += bf_lo(v0); a1 += bf_hi(v0);
    }
    float dn = dis[wid];
    unsigned int pack = (unsigned int)f2bf(a0 * dn) | ((unsigned int)f2bf(a1 * dn) << 16);
    ((unsigned int*)aggh)[((size_t)wid << 6) + lane] = pack;
}

__global__ __launch_bounds__(256) void k_mm(
        const unsigned short* __restrict__ aggh, const unsigned short* __restrict__ w1t,
        const float* __restrict__ b1, const float* __restrict__ W2,
        const float* __restrict__ dis, float* __restrict__ svs, int n) {
    int wave = threadIdx.x >> 6;
    int lane = threadIdx.x & 63;
    int m = lane & 15, quad = lane >> 4;
    int node0 = blockIdx.x * 64 + wave * 16;
    bf16x8 afrag[4];
    const unsigned short* arow = aggh + (size_t)(node0 + m) * 128 + quad * 8;
#pragma unroll
    for (int ks = 0; ks < 4; ++ks) afrag[ks] = *(const bf16x8*)(arow + ks * 32);
    float p0 = 0.f, p1 = 0.f, p2 = 0.f, p3 = 0.f;
#pragma unroll 1
    for (int tt = 0; tt < 16; ++tt) {
        const unsigned short* brow = w1t + (size_t)(tt * 16 + m) * 128 + quad * 8;
        f32x4 acc = {0.f, 0.f, 0.f, 0.f};
#pragma unroll
        for (int ks = 0; ks < 4; ++ks) {
            bf16x8 bfrag = *(const bf16x8*)(brow + ks * 32);
            acc = __builtin_amdgcn_mfma_f32_16x16x32_bf16(afrag[ks], bfrag, acc, 0, 0, 0);
        }
        int col = tt * 16 + m;
        float bb = b1[col], w2 = W2[col];
        float h0 = acc[0] + bb, h1 = acc[1] + bb, h2 = acc[2] + bb, h3 = acc[3] + bb;
        p0 += (h0 > 0.f ? h0 : 0.f) * w2;
        p1 += (h1 > 0.f ? h1 : 0.f) * w2;
        p2 += (h2 > 0.f ? h2 : 0.f) * w2;
        p3 += (h3 > 0.f ? h3 : 0.f) * w2;
    }
#pragma unroll
    for (int off = 1; off < 16; off <<= 1) {
        p0 += __shfl_xor(p0, off, 64);
        p1 += __shfl_xor(p1, off, 64);
        p2 += __shfl_xor(p2, off, 64);
        p3 += __shfl_xor(p3, off, 64);
    }
    if (m == 0) {
        int nb = node0 + quad * 4;
        if (nb + 0 < n) svs[nb + 0] = p0 * dis[nb + 0];
        if (nb + 1 < n) svs[nb + 1] = p1 * dis[nb + 1];
        if (nb + 2 < n) svs[nb + 2] = p2 * dis[nb + 2];
        if (nb + 3 < n) svs[nb + 3] = p3 * dis[nb + 3];
    }
}

__global__ __launch_bounds__(256) void k_out(
        const float* __restrict__ svs, const int* __restrict__ csr_src,
        const int* __restrict__ row_start, const float* __restrict__ dis,
        const float* __restrict__ b2, float* __restrict__ out, int n) {
    int wid  = (blockIdx.x * blockDim.x + threadIdx.x) >> 6;
    int lane = threadIdx.x & 63;
    if (wid >= n) return;
    int start = row_start[wid], end = row_start[wid + 1];
    float acc = 0.f;
    for (int e = start + lane; e < end; e += 64)
        acc += svs[csr_src[e]];
    for (int off = 32; off; off >>= 1) acc += __shfl_down(acc, off, 64);
    if (lane == 0)
        out[wid] = dis[wid] * (acc + svs[wid]) + b2[0];
}

// ---------------- slow fallback (n >= 65536; never for this problem) -------
__global__ void k_init(const int* __restrict__ edges, int* __restrict__ flag,
                       int* __restrict__ cnt, int n) {
    int i = blockIdx.x * blockDim.x + threadIdx.x;
    if (i < n) cnt[i] = 0;
    if (blockIdx.x == 0 && threadIdx.x < 64) {
        int v = edges[2 * threadIdx.x + 1];
        unsigned long long b = __ballot(v != 0);
        if (threadIdx.x == 0) flag[0] = b ? 1 : 2;
    }
}
__global__ __launch_bounds__(256) void k_prep_xs(const float* __restrict__ x,
        const float* __restrict__ dis, unsigned short* __restrict__ xs, int n) {
    int i = blockIdx.x * 256 + threadIdx.x;
    if (i >= n * 32) return;
    float dsc = dis[i >> 5];
    float4 v = ((const float4*)x)[i];
    ushort4 o;
    o.x = f2bf(v.x * dsc); o.y = f2bf(v.y * dsc);
    o.z = f2bf(v.z * dsc); o.w = f2bf(v.w * dsc);
    ((ushort4*)xs)[i] = o;
}
__global__ __launch_bounds__(128) void k_prep_w(const float* __restrict__ W1,
        unsigned short* __restrict__ w1t) {
    int nn = blockIdx.x, k = threadIdx.x;
    w1t[nn * 128 + k] = f2bf(W1[k * 256 + nn]);
}
__global__ void k_count_slow(const int* __restrict__ edges, const int* __restrict__ flag,
                             int* __restrict__ cnt, int* __restrict__ posi, long long E) {
    long long e = (long long)blockIdx.x * blockDim.x + threadIdx.x;
    if (e >= E) return;
    int stride = flag[0];
    int d = edges[(E + e) * stride];
    posi[e] = atomicAdd(&cnt[d], 1);
}
__global__ __launch_bounds__(256) void k_scan_partial(
        const int* __restrict__ cnt, int* __restrict__ bsum, int n) {
    int t = threadIdx.x;
    int idx = blockIdx.x * SCAN_TILE + t * 8;
    int s = 0;
#pragma unroll
    for (int j = 0; j < 8; ++j) { int i = idx + j; if (i < n) s += cnt[i]; }
    for (int off = 32; off; off >>= 1) s += __shfl_down(s, off, 64);
    __shared__ int ws[4];
    if ((t & 63) == 0) ws[t >> 6] = s;
    __syncthreads();
    if (t == 0) bsum[blockIdx.x] = ws[0] + ws[1] + ws[2] + ws[3];
}
__global__ void k_scan_tops(int* __restrict__ bsum, int nb) {
    int t = threadIdx.x;
    int w = (t < nb) ? bsum[t] : 0;
    int v = w;
    for (int off = 1; off < 64; off <<= 1) {
        int u = __shfl_up(v, off, 64);
        if (t >= off) v += u;
    }
    if (t < nb) bsum[t] = v - w;
}
__global__ __launch_bounds__(256) void k_scan_apply(
        const int* __restrict__ cnt, const int* __restrict__ bsum,
        int* __restrict__ row_start, float* __restrict__ dis, int n) {
    int t = threadIdx.x;
    int lane = t & 63, w = t >> 6;
    int idx = blockIdx.x * SCAN_TILE + t * 8;
    int vals[8];
    int s = 0;
#pragma unroll
    for (int j = 0; j < 8; ++j) { int i = idx + j; vals[j] = (i < n) ? cnt[i] : 0; s += vals[j]; }
    int inc = s;
    for (int off = 1; off < 64; off <<= 1) {
        int u = __shfl_up(inc, off, 64);
        if (lane >= off) inc += u;
    }
    __shared__ int wsum[4];
    if (lane == 63) wsum[w] = inc;
    __syncthreads();
    int woff = 0;
    for (int i = 0; i < w; ++i) woff += wsum[i];
    int ex = bsum[blockIdx.x] + woff + inc - s;
#pragma unroll
    for (int j = 0; j < 8; ++j) {
        int i = idx + j;
        if (i < n) {
            row_start[i] = ex;
            dis[i] = rsqrtf((float)vals[j] + 1.0f);
            ex += vals[j];
        }
    }
    if (idx <= n && n < idx + 8) row_start[n] = ex;
}
__global__ void k_scatter_slow(const int* __restrict__ edges, const int* __restrict__ flag,
                               const int* __restrict__ row_start, const int* __restrict__ posi,
                               int* __restrict__ csr_src, long long E) {
    long long e = (long long)blockIdx.x * blockDim.x + threadIdx.x;
    if (e >= E) return;
    int stride = flag[0];
    int s = edges[e * stride];
    int d = edges[(E + e) * stride];
    csr_src[row_start[d] + posi[e]] = s;
}
// ---------------------------------------------------------------------------

extern "C" void kernel_launch(void* const* d_in, const int* in_sizes, int n_in,
                              void* d_out, int out_size, void* d_ws, size_t ws_size,
                              hipStream_t stream) {
    const float* x  = (const float*)d_in[0];
    const int*   ei = (const int*)d_in[1];
    const float* W1 = (const float*)d_in[2];
    const float* b1 = (const float*)d_in[3];
    const float* W2 = (const float*)d_in[4];
    const float* b2 = (const float*)d_in[5];
    float* out = (float*)d_out;

    const int N = in_sizes[0] / 128;
    const long long E = in_sizes[1] / 2;
    const int nsb = (int)((E + EPB - 1) >> EPB_LOG);
    const int nbuck = (N + BW - 1) >> BW_LOG;

    char* ws = (char*)d_ws;
    size_t off = 0;
    auto take = [&](size_t bytes) -> char* {
        char* p = ws + off;
        off = (off + bytes + 255) & ~(size_t)255;
        return p;
    };
    int*            flag     = (int*)take(4);
    int*            cnt      = (int*)take((size_t)N * 4);
    int*            rs       = (int*)take((size_t)(N + 1) * 4);
    float*          dis      = (float*)take((size_t)N * 4);
    float*          svs      = (float*)take((size_t)N * 4);
    int*            bsum     = (int*)take(64 * 4);
    int*            btot_raw = (int*)take(MAXBUCK * 4);
    int*            btot     = (int*)take(MAXBUCK * 4);
    int*            curg     = (int*)take(MAXBUCK * 4);
    unsigned int*   part     = (unsigned int*)take((size_t)E * 4);
    int*            csr_src  = (int*)take((size_t)E * 4);
    unsigned short* xs       = (unsigned short*)take((size_t)N * 128 * 2);
    unsigned short* w1t      = (unsigned short*)take((size_t)256 * 128 * 2);
    unsigned short* aggh     = (unsigned short*)take((size_t)(N + 64) * 128 * 2);

    int nb_n  = (N + 255) / 256;
    int nb_e  = (int)((E + 255) / 256);
    int nb_s  = (N + SCAN_TILE - 1) / SCAN_TILE;
    int nb_x  = (N * 32 + 255) / 256;

    bool fast = (N < 65536);

    bool coop_done = false;
    if (fast) {
        // grid size: all blocks must be co-resident for grid.sync()
        int dev = 0;
        (void)hipGetDevice(&dev);
        int numCU = 0;
        (void)hipDeviceGetAttribute(&numCU, hipDeviceAttributeMultiprocessorCount, dev);
        int perCU = 0;
        (void)hipOccupancyMaxActiveBlocksPerMultiprocessor(&perCU, k_all, 256, 0);
        long long nbL = (long long)perCU * (numCU > 0 ? numCU : 0);
        int NB = (int)(nbL > 2048 ? 2048 : nbL);
        if (NB > 0) {
            int n_ = N; long long E_ = E; int nsb_ = nsb; int nbuck_ = nbuck;
            void* args[] = { (void*)&ei, (void*)&x, (void*)&W1, (void*)&b1,
                             (void*)&W2, (void*)&b2, (void*)&out, (void*)&w1t,
                             (void*)&btot_raw, (void*)&btot, (void*)&curg,
                             (void*)&part, (void*)&csr_src, (void*)&xs,
                             (void*)&rs, (void*)&dis, (void*)&svs, (void*)&aggh,
                             (void*)&n_, (void*)&E_, (void*)&nsb_, (void*)&nbuck_ };
            hipError_t err = hipLaunchCooperativeKernel((void*)k_all, dim3(NB),
                                                        dim3(256), args, 0, stream);
            coop_done = (err == hipSuccess);
        }
    }

    if (fast && !coop_done) {
        // R11's proven 8-launch chain (identical math)
        hipMemsetAsync(btot_raw, 0, (size_t)nbuck * 4, stream);
        k_count    <<<nsb + 128, 256, 0, stream>>>(ei, W1, w1t, btot_raw, E, nbuck, nsb);
        k_btot_scan<<<1, 256, 0, stream>>>(btot_raw, btot, curg, nbuck);
        k_partition<<<nsb, 256, 0, stream>>>(ei, curg, part, E, nbuck);
        k_build_csr<<<nbuck, 256, 0, stream>>>(part, btot, x, rs, dis, csr_src,
                                               xs, nbuck, N, E);
        k_agg      <<<(N + 3) / 4, 256, 0, stream>>>(xs, csr_src, rs, dis, aggh, N);
        k_mm       <<<(N + 63) / 64, 256, 0, stream>>>(aggh, w1t, b1, W2, dis, svs, N);
        k_out      <<<(N + 3) / 4, 256, 0, stream>>>(svs, csr_src, rs, dis, b2, out, N);
    } else if (!fast) {
        k_init        <<<nb_n, 256, 0, stream>>>(ei, flag, cnt, N);
        k_prep_w      <<<256, 128, 0, stream>>>(W1, w1t);
        k_count_slow  <<<nb_e, 256, 0, stream>>>(ei, flag, cnt, (int*)part, E);
        k_scan_partial<<<nb_s, 256, 0, stream>>>(cnt, bsum, N);
        k_scan_tops   <<<1, 64, 0, stream>>>(bsum, nb_s);
        k_scan_apply  <<<nb_s, 256, 0, stream>>>(cnt, bsum, rs, dis, N);
        k_prep_xs     <<<nb_x, 256, 0, stream>>>(x, dis, xs, N);
        k_scatter_slow<<<nb_e, 256, 0, stream>>>(ei, flag, rs, (const int*)part, csr_src, E);
        k_agg         <<<(N + 3) / 4, 256, 0, stream>>>(xs, csr_src, rs, dis, aggh, N);
        k_mm          <<<(N + 63) / 64, 256, 0, stream>>>(aggh, w1t, b1, W2, dis, svs, N);
        k_out         <<<(N + 3) / 4, 256, 0, stream>>>(svs, csr_src, rs, dis, b2, out, N);
    }
}

// Round 15
// 240.705 us; speedup vs baseline: 3.4369x; 3.4369x over previous
//
#include <hip/hip_runtime.h>

// ---------------------------------------------------------------------------
// GCN: out = A_norm * relu(A_norm * X * W1 + b1) * W2 + b2
// A_norm = D^-1/2 (A + I) D^-1/2, built from 1.6M random edges + self loops.
//
// Round-15: back to the proven R11 8-launch chain. One change: k_agg becomes
// feature-split two-pass (xs_lo/xs_hi, 6.4MB each vs 12.8MB combined). Blocks
// [0,NBH) gather the low 64 features, [NBH,2NBH) the high 64 -> per-phase
// working set halves -> L2 hit rate up, fabric traffic (the 56us wall) down.
// Half-wave (32 lanes) per node per half; 128B coalesced row loads; per-node
// per-feature accumulation order is bitwise identical to R11.
// Disproven & banned: agg+mm fusion-by-barrier (R10 89us / R13 97us vs 60us
// split); cooperative grid.sync mega-kernel (R14: 827us); LDS float atomics
// as accumulator (R8: 1350us).
// ---------------------------------------------------------------------------

#define EPB_LOG 12
#define EPB (1 << EPB_LOG)     // 4096 edges per partition block
#define BW_LOG 7
#define BW (1 << BW_LOG)       // 128 dst nodes per bucket
#define MAXBUCK 512            // fast path: n <= 65536
#define SCAN_TILE 2048

typedef __attribute__((ext_vector_type(8))) short bf16x8;
typedef __attribute__((ext_vector_type(4))) float f32x4;

__device__ inline unsigned short f2bf(float f) {
    unsigned int b = __float_as_uint(f);
    unsigned int r = b + 0x7FFFu + ((b >> 16) & 1u);   // round-to-nearest-even
    return (unsigned short)(r >> 16);
}
__device__ inline float bf_lo(unsigned int u) { return __uint_as_float(u << 16); }
__device__ inline float bf_hi(unsigned int u) { return __uint_as_float(u & 0xFFFF0000u); }

// Self-detect int64-vs-int32 edge storage from the first 64 odd words.
__device__ inline int detect_stride(const int* edges, int t, int* sh) {
    if (t < 64) {
        int v = edges[2 * t + 1];
        unsigned long long bb = __ballot(v != 0);
        if (t == 0) *sh = bb ? 1 : 2;
    }
    __syncthreads();
    return *sh;
}

// ---------------- fast path ------------------------------------------------

// Blocks [0,nsb): per-block LDS bucket hist -> global atomic flush.
// Blocks [nsb, nsb+128): W1 [128][256] fp32 -> w1t [256][128] bf16 (2 rows/blk).
__global__ __launch_bounds__(256) void k_count(
        const int* __restrict__ edges, const float* __restrict__ W1,
        unsigned short* __restrict__ w1t, int* __restrict__ btot_raw,
        long long E, int nbuck, int nsb) {
    int b = blockIdx.x, t = threadIdx.x;
    if (b >= nsb) {
        int row = (b - nsb) * 2 + (t >> 7);
        int k = t & 127;
        w1t[row * 128 + k] = f2bf(W1[k * 256 + row]);
        return;
    }
    __shared__ int bins[MAXBUCK];
    __shared__ int sh;
    for (int i = t; i < nbuck; i += 256) bins[i] = 0;
    int stride = detect_stride(edges, t, &sh);   // has a __syncthreads
    long long base = (long long)b << EPB_LOG;
    long long rem = E - base;
    int nE = (rem < (long long)EPB) ? (int)rem : EPB;
    for (int i = t; i < nE; i += 256) {
        int d = edges[(E + base + i) * stride];
        atomicAdd(&bins[d >> BW_LOG], 1);
    }
    __syncthreads();
    for (int i = t; i < nbuck; i += 256)
        if (bins[i]) atomicAdd(&btot_raw[i], bins[i]);
}

// One block: exclusive scan of bucket totals -> btot; init global cursors.
__global__ __launch_bounds__(256) void k_btot_scan(
        const int* __restrict__ btot_raw, int* __restrict__ btot,
        int* __restrict__ curg, int nbuck) {
    __shared__ int ws4[4];
    int t = threadIdx.x;
    int c4 = (nbuck + 255) >> 8;     // <=2
    int lo = t * c4;
    int hi = lo + c4; if (hi > nbuck) hi = nbuck;
    if (lo > nbuck) lo = nbuck;
    int vals[2];
    int local = 0;
    for (int i = lo; i < hi; ++i) { vals[i - lo] = btot_raw[i]; local += vals[i - lo]; }
    int lane = t & 63, w = t >> 6;
    int inc = local;
    for (int off = 1; off < 64; off <<= 1) {
        int u = __shfl_up(inc, off, 64);
        if (lane >= off) inc += u;
    }
    if (lane == 63) ws4[w] = inc;
    __syncthreads();
    int woff = 0;
    for (int i = 0; i < w; ++i) woff += ws4[i];
    int ex = woff + inc - local;
    for (int i = lo; i < hi; ++i) {
        btot[i] = ex; curg[i] = ex;
        ex += vals[i - lo];
    }
}

// Partition 4096 edges into bucket-contiguous packed (src<<16|dst) stream.
__global__ __launch_bounds__(256) void k_partition(
        const int* __restrict__ edges, int* __restrict__ curg,
        unsigned int* __restrict__ part, long long E, int nbuck) {
    __shared__ unsigned int stage[EPB];       // 16 KB
    __shared__ unsigned short dst16[EPB];     // 8 KB
    __shared__ int bins[MAXBUCK];
    __shared__ int lcur[MAXBUCK];
    __shared__ int gbase[MAXBUCK];
    __shared__ int ws4[4];
    __shared__ int sh;
    int sb = blockIdx.x, t = threadIdx.x;
    for (int i = t; i < nbuck; i += 256) bins[i] = 0;
    int stride = detect_stride(edges, t, &sh);
    long long base = (long long)sb << EPB_LOG;
    long long rem = E - base;
    int nE = (rem < (long long)EPB) ? (int)rem : EPB;
    for (int i = t; i < nE; i += 256) {
        int d = edges[(E + base + i) * stride];
        dst16[i] = (unsigned short)d;
        atomicAdd(&bins[d >> BW_LOG], 1);
    }
    __syncthreads();
    // read counts for local scan BEFORE any in-place overwrite
    int c4 = (nbuck + 255) >> 8;          // <=2
    int lo = t * c4;
    int hi = lo + c4; if (hi > nbuck) hi = nbuck;
    if (lo > nbuck) lo = nbuck;
    int vals[2];
    int local = 0;
    for (int i = lo; i < hi; ++i) { vals[i - lo] = bins[i]; local += vals[i - lo]; }
    // reserve global space (bins still holds counts)
    for (int i = t; i < nbuck; i += 256) {
        int c = bins[i];
        gbase[i] = c ? atomicAdd(&curg[i], c) : 0;
    }
    __syncthreads();   // all count reads done before offsets overwrite bins
    int lane = t & 63, w = t >> 6;
    int inc = local;
    for (int off = 1; off < 64; off <<= 1) {
        int u = __shfl_up(inc, off, 64);
        if (lane >= off) inc += u;
    }
    if (lane == 63) ws4[w] = inc;
    __syncthreads();
    int woff = 0;
    for (int i = 0; i < w; ++i) woff += ws4[i];
    int ex = woff + inc - local;
    for (int i = lo; i < hi; ++i) {
        bins[i] = ex;        // local exclusive offset (kept for flush)
        lcur[i] = ex;        // running cursor
        ex += vals[i - lo];
    }
    __syncthreads();
    // place pass into LDS stage (src from global, dst from LDS)
    for (int i = t; i < nE; i += 256) {
        int s = edges[(base + i) * stride];
        int d = dst16[i];
        int b = d >> BW_LOG;
        int p = atomicAdd(&lcur[b], 1);
        stage[p] = ((unsigned int)s << 16) | (unsigned int)d;
    }
    __syncthreads();
    // flush: consecutive i -> same-bucket runs -> coalesced global writes
    for (int i = t; i < nE; i += 256) {
        unsigned int pk = stage[i];
        int b = (int)(pk & 0xFFFFu) >> BW_LOG;
        part[gbase[b] + (i - bins[b])] = pk;
    }
}

// Per-bucket: deg -> dis + row_start (local scan), csr ranks, and split-xs
// conversion for this bucket's own 128 nodes. One block per bucket.
__global__ __launch_bounds__(256) void k_build_csr(
        const unsigned int* __restrict__ part, const int* __restrict__ btot,
        const float* __restrict__ x, int* __restrict__ row_start,
        float* __restrict__ dis, int* __restrict__ csr_src,
        unsigned short* __restrict__ xs_lo, unsigned short* __restrict__ xs_hi,
        int nbuck, int n, long long E) {
    __shared__ int c128[BW];
    __shared__ int lcur[BW];
    __shared__ float dld[BW];
    __shared__ int ws2[2];
    int b = blockIdx.x, t = threadIdx.x;
    if (t < BW) c128[t] = 0;
    __syncthreads();
    int start = btot[b];
    int endp = (b + 1 < nbuck) ? btot[b + 1] : (int)E;
    for (int i = start + t; i < endp; i += 256)
        atomicAdd(&c128[part[i] & (BW - 1)], 1);
    __syncthreads();
    int lane = t & 63, w = t >> 6;
    int deg = (t < BW) ? c128[t] : 0;
    int inc = deg;
    for (int off = 1; off < 64; off <<= 1) {
        int u = __shfl_up(inc, off, 64);
        if (lane >= off) inc += u;
    }
    if (t < BW && lane == 63) ws2[w] = inc;
    __syncthreads();
    if (t < BW) {
        int ex = inc - deg + ((w == 1) ? ws2[0] : 0);
        lcur[t] = ex;
        int d = (b << BW_LOG) + t;
        if (d < n) {
            row_start[d] = start + ex;
            float dv = rsqrtf((float)deg + 1.0f);   // +1 = self loop
            dis[d] = dv;
            dld[t] = dv;
        }
    }
    if (b == nbuck - 1 && t == 0) row_start[n] = (int)E;   // CSR sentinel
    __syncthreads();
    // rank pass: csr_src stores land in this bucket's contiguous window
    for (int i = start + t; i < endp; i += 256) {
        unsigned int pk = part[i];
        int r = atomicAdd(&lcur[pk & (BW - 1)], 1);
        csr_src[start + r] = (int)(pk >> 16);
    }
    // split xs = bf16(dis * x): ushort4 group g covers features 4g..4g+3;
    // g<16 -> xs_lo (features 0..63), g>=16 -> xs_hi (features 64..127).
    int d0 = b << BW_LOG;
    for (int idx = t; idx < BW * 32; idx += 256) {
        int node = d0 + (idx >> 5);
        if (node >= n) break;
        int g = idx & 31;
        float dv = dld[idx >> 5];
        float4 v = ((const float4*)x)[(size_t)node * 32 + g];
        ushort4 o;
        o.x = f2bf(v.x * dv); o.y = f2bf(v.y * dv);
        o.z = f2bf(v.z * dv); o.w = f2bf(v.w * dv);
        if (g < 16) ((ushort4*)xs_lo)[(size_t)node * 16 + g] = o;
        else        ((ushort4*)xs_hi)[(size_t)node * 16 + (g - 16)] = o;
    }
}

// Feature-split aggregate. Blocks [0,NBH): low 64 features from xs_lo;
// blocks [NBH,2*NBH): high 64 from xs_hi (phase separation halves the L2
// working set: 6.4MB per phase). Half-wave (32 lanes) per node; per-lane
// uint = 2 features; 128B coalesced row loads; 8-edge unroll.
__global__ __launch_bounds__(256) void k_agg_split(
        const unsigned short* __restrict__ xs_lo,
        const unsigned short* __restrict__ xs_hi,
        const int* __restrict__ csr_src, const int* __restrict__ rs,
        const float* __restrict__ dis, unsigned short* __restrict__ aggh,
        int n, int NBH) {
    int half = (blockIdx.x < NBH) ? 0 : 1;
    int bi   = (half == 0) ? blockIdx.x : blockIdx.x - NBH;
    int t = threadIdx.x;
    int lane = t & 63, w = t >> 6;
    int hw = lane >> 5;            // which half-wave
    int hl = lane & 31;            // lane within half-wave
    int node = bi * 8 + w * 2 + hw;
    if (node >= n) return;
    const unsigned int* xsu = (const unsigned int*)(half ? xs_hi : xs_lo);
    int start = rs[node], end = rs[node + 1];
    unsigned int self = xsu[((size_t)node << 5) + hl];
    float a0 = bf_lo(self), a1 = bf_hi(self);
    int e = start;
    for (; e + 7 < end; e += 8) {
        int s0 = csr_src[e],     s1 = csr_src[e + 1];
        int s2 = csr_src[e + 2], s3 = csr_src[e + 3];
        int s4 = csr_src[e + 4], s5 = csr_src[e + 5];
        int s6 = csr_src[e + 6], s7 = csr_src[e + 7];
        unsigned int v0 = xsu[((size_t)s0 << 5) + hl];
        unsigned int v1 = xsu[((size_t)s1 << 5) + hl];
        unsigned int v2 = xsu[((size_t)s2 << 5) + hl];
        unsigned int v3 = xsu[((size_t)s3 << 5) + hl];
        unsigned int v4 = xsu[((size_t)s4 << 5) + hl];
        unsigned int v5 = xsu[((size_t)s5 << 5) + hl];
        unsigned int v6 = xsu[((size_t)s6 << 5) + hl];
        unsigned int v7 = xsu[((size_t)s7 << 5) + hl];
        a0 += bf_lo(v0); a1 += bf_hi(v0);
        a0 += bf_lo(v1); a1 += bf_hi(v1);
        a0 += bf_lo(v2); a1 += bf_hi(v2);
        a0 += bf_lo(v3); a1 += bf_hi(v3);
        a0 += bf_lo(v4); a1 += bf_hi(v4);
        a0 += bf_lo(v5); a1 += bf_hi(v5);
        a0 += bf_lo(v6); a1 += bf_hi(v6);
        a0 += bf_lo(v7); a1 += bf_hi(v7);
    }
    for (; e < end; ++e) {
        int s0 = csr_src[e];
        unsigned int v0 = xsu[((size_t)s0 << 5) + hl];
        a0 += bf_lo(v0); a1 += bf_hi(v0);
    }
    float dn = dis[node];
    unsigned int pack = (unsigned int)f2bf(a0 * dn) | ((unsigned int)f2bf(a1 * dn) << 16);
    // aggh uint layout: node*64 + half*32 + hl  (identical to combined layout)
    ((unsigned int*)aggh)[((size_t)node << 6) + (half << 5) + hl] = pack;
}

// MFMA GEMM: svs = dis * (relu(agg @ W1 + b1) @ W2).
__global__ __launch_bounds__(256) void k_mm(
        const unsigned short* __restrict__ aggh, const unsigned short* __restrict__ w1t,
        const float* __restrict__ b1, const float* __restrict__ W2,
        const float* __restrict__ dis, float* __restrict__ svs, int n) {
    int wave = threadIdx.x >> 6;        // 0..3
    int lane = threadIdx.x & 63;
    int m    = lane & 15;
    int quad = lane >> 4;               // 0..3
    int node0 = blockIdx.x * 64 + wave * 16;

    bf16x8 afrag[4];
    const unsigned short* arow = aggh + (size_t)(node0 + m) * 128 + quad * 8;
#pragma unroll
    for (int ks = 0; ks < 4; ++ks)
        afrag[ks] = *(const bf16x8*)(arow + ks * 32);

    float p0 = 0.f, p1 = 0.f, p2 = 0.f, p3 = 0.f;
#pragma unroll 1
    for (int tt = 0; tt < 16; ++tt) {
        const unsigned short* brow = w1t + (size_t)(tt * 16 + m) * 128 + quad * 8;
        f32x4 acc = {0.f, 0.f, 0.f, 0.f};
#pragma unroll
        for (int ks = 0; ks < 4; ++ks) {
            bf16x8 bfrag = *(const bf16x8*)(brow + ks * 32);
            acc = __builtin_amdgcn_mfma_f32_16x16x32_bf16(afrag[ks], bfrag, acc, 0, 0, 0);
        }
        int col = tt * 16 + m;
        float bb = b1[col], w2 = W2[col];
        float h0 = acc[0] + bb, h1 = acc[1] + bb, h2 = acc[2] + bb, h3 = acc[3] + bb;
        p0 += (h0 > 0.f ? h0 : 0.f) * w2;
        p1 += (h1 > 0.f ? h1 : 0.f) * w2;
        p2 += (h2 > 0.f ? h2 : 0.f) * w2;
        p3 += (h3 > 0.f ? h3 : 0.f) * w2;
    }
#pragma unroll
    for (int off = 1; off < 16; off <<= 1) {
        p0 += __shfl_xor(p0, off, 64);
        p1 += __shfl_xor(p1, off, 64);
        p2 += __shfl_xor(p2, off, 64);
        p3 += __shfl_xor(p3, off, 64);
    }
    if (m == 0) {
        int nb = node0 + quad * 4;
        if (nb + 0 < n) svs[nb + 0] = p0 * dis[nb + 0];
        if (nb + 1 < n) svs[nb + 1] = p1 * dis[nb + 1];
        if (nb + 2 < n) svs[nb + 2] = p2 * dis[nb + 2];
        if (nb + 3 < n) svs[nb + 3] = p3 * dis[nb + 3];
    }
}

// out[i] = b2 + dn_i * (sum_e svs[src_e] + svs[i]); wave per node.
__global__ __launch_bounds__(256) void k_out(
        const float* __restrict__ svs, const int* __restrict__ csr_src,
        const int* __restrict__ row_start, const float* __restrict__ dis,
        const float* __restrict__ b2, float* __restrict__ out, int n) {
    int wid  = (blockIdx.x * blockDim.x + threadIdx.x) >> 6;
    int lane = threadIdx.x & 63;
    if (wid >= n) return;
    int start = row_start[wid], end = row_start[wid + 1];
    float acc = 0.f;
    for (int e = start + lane; e < end; e += 64)
        acc += svs[csr_src[e]];
    for (int off = 32; off; off >>= 1) acc += __shfl_down(acc, off, 64);
    if (lane == 0)
        out[wid] = dis[wid] * (acc + svs[wid]) + b2[0];
}

// ---------------- fallback path (n >= 65536; never for this problem) -------
__global__ void k_init(const int* __restrict__ edges, int* __restrict__ flag,
                       int* __restrict__ cnt, int n) {
    int i = blockIdx.x * blockDim.x + threadIdx.x;
    if (i < n) cnt[i] = 0;
    if (blockIdx.x == 0 && threadIdx.x < 64) {
        int v = edges[2 * threadIdx.x + 1];
        unsigned long long b = __ballot(v != 0);
        if (threadIdx.x == 0) flag[0] = b ? 1 : 2;
    }
}
// Split-array xs prep for the slow path (keeps fast-path layout).
__global__ __launch_bounds__(256) void k_prep_xs(const float* __restrict__ x,
        const float* __restrict__ dis, unsigned short* __restrict__ xs_lo,
        unsigned short* __restrict__ xs_hi, int n) {
    int i = blockIdx.x * 256 + threadIdx.x;
    if (i >= n * 32) return;
    int node = i >> 5, g = i & 31;
    float dsc = dis[node];
    float4 v = ((const float4*)x)[i];
    ushort4 o;
    o.x = f2bf(v.x * dsc); o.y = f2bf(v.y * dsc);
    o.z = f2bf(v.z * dsc); o.w = f2bf(v.w * dsc);
    if (g < 16) ((ushort4*)xs_lo)[(size_t)node * 16 + g] = o;
    else        ((ushort4*)xs_hi)[(size_t)node * 16 + (g - 16)] = o;
}
__global__ __launch_bounds__(128) void k_prep_w(const float* __restrict__ W1,
        unsigned short* __restrict__ w1t) {
    int nn = blockIdx.x, k = threadIdx.x;
    w1t[nn * 128 + k] = f2bf(W1[k * 256 + nn]);
}
__global__ void k_count_slow(const int* __restrict__ edges, const int* __restrict__ flag,
                             int* __restrict__ cnt, int* __restrict__ posi, long long E) {
    long long e = (long long)blockIdx.x * blockDim.x + threadIdx.x;
    if (e >= E) return;
    int stride = flag[0];
    int d = edges[(E + e) * stride];
    posi[e] = atomicAdd(&cnt[d], 1);
}
__global__ __launch_bounds__(256) void k_scan_partial(
        const int* __restrict__ cnt, int* __restrict__ bsum, int n) {
    int t = threadIdx.x;
    int idx = blockIdx.x * SCAN_TILE + t * 8;
    int s = 0;
#pragma unroll
    for (int j = 0; j < 8; ++j) { int i = idx + j; if (i < n) s += cnt[i]; }
    for (int off = 32; off; off >>= 1) s += __shfl_down(s, off, 64);
    __shared__ int ws[4];
    if ((t & 63) == 0) ws[t >> 6] = s;
    __syncthreads();
    if (t == 0) bsum[blockIdx.x] = ws[0] + ws[1] + ws[2] + ws[3];
}
__global__ void k_scan_tops(int* __restrict__ bsum, int nb) {
    int t = threadIdx.x;
    int w = (t < nb) ? bsum[t] : 0;
    int v = w;
    for (int off = 1; off < 64; off <<= 1) {
        int u = __shfl_up(v, off, 64);
        if (t >= off) v += u;
    }
    if (t < nb) bsum[t] = v - w;
}
__global__ __launch_bounds__(256) void k_scan_apply(
        const int* __restrict__ cnt, const int* __restrict__ bsum,
        int* __restrict__ row_start, float* __restrict__ dis, int n) {
    int t = threadIdx.x;
    int lane = t & 63, w = t >> 6;
    int idx = blockIdx.x * SCAN_TILE + t * 8;
    int vals[8];
    int s = 0;
#pragma unroll
    for (int j = 0; j < 8; ++j) { int i = idx + j; vals[j] = (i < n) ? cnt[i] : 0; s += vals[j]; }
    int inc = s;
    for (int off = 1; off < 64; off <<= 1) {
        int u = __shfl_up(inc, off, 64);
        if (lane >= off) inc += u;
    }
    __shared__ int wsum[4];
    if (lane == 63) wsum[w] = inc;
    __syncthreads();
    int woff = 0;
    for (int i = 0; i < w; ++i) woff += wsum[i];
    int ex = bsum[blockIdx.x] + woff + inc - s;
#pragma unroll
    for (int j = 0; j < 8; ++j) {
        int i = idx + j;
        if (i < n) {
            row_start[i] = ex;
            dis[i] = rsqrtf((float)vals[j] + 1.0f);
            ex += vals[j];
        }
    }
    if (idx <= n && n < idx + 8) row_start[n] = ex;
}
__global__ void k_scatter_slow(const int* __restrict__ edges, const int* __restrict__ flag,
                               const int* __restrict__ row_start, const int* __restrict__ posi,
                               int* __restrict__ csr_src, long long E) {
    long long e = (long long)blockIdx.x * blockDim.x + threadIdx.x;
    if (e >= E) return;
    int stride = flag[0];
    int s = edges[e * stride];
    int d = edges[(E + e) * stride];
    csr_src[row_start[d] + posi[e]] = s;
}
// ---------------------------------------------------------------------------

extern "C" void kernel_launch(void* const* d_in, const int* in_sizes, int n_in,
                              void* d_out, int out_size, void* d_ws, size_t ws_size,
                              hipStream_t stream) {
    const float* x  = (const float*)d_in[0];
    const int*   ei = (const int*)d_in[1];
    const float* W1 = (const float*)d_in[2];
    const float* b1 = (const float*)d_in[3];
    const float* W2 = (const float*)d_in[4];
    const float* b2 = (const float*)d_in[5];
    float* out = (float*)d_out;

    const int N = in_sizes[0] / 128;
    const long long E = in_sizes[1] / 2;
    const int nsb = (int)((E + EPB - 1) >> EPB_LOG);   // 391 partition blocks
    const int nbuck = (N + BW - 1) >> BW_LOG;          // 391 buckets for N=50000

    char* ws = (char*)d_ws;
    size_t off = 0;
    auto take = [&](size_t bytes) -> char* {
        char* p = ws + off;
        off = (off + bytes + 255) & ~(size_t)255;
        return p;
    };
    int*            flag     = (int*)take(4);
    int*            cnt      = (int*)take((size_t)N * 4);
    int*            rs       = (int*)take((size_t)(N + 1) * 4);
    float*          dis      = (float*)take((size_t)N * 4);
    float*          svs      = (float*)take((size_t)N * 4);
    int*            bsum     = (int*)take(64 * 4);
    int*            btot_raw = (int*)take(MAXBUCK * 4);
    int*            btot     = (int*)take(MAXBUCK * 4);
    int*            curg     = (int*)take(MAXBUCK * 4);
    unsigned int*   part     = (unsigned int*)take((size_t)E * 4);  // packed / posi slow
    int*            csr_src  = (int*)take((size_t)E * 4);
    unsigned short* xs_lo    = (unsigned short*)take((size_t)N * 64 * 2);
    unsigned short* xs_hi    = (unsigned short*)take((size_t)N * 64 * 2);
    unsigned short* w1t      = (unsigned short*)take((size_t)256 * 128 * 2);
    unsigned short* aggh     = (unsigned short*)take((size_t)(N + 64) * 128 * 2);

    int nb_n  = (N + 255) / 256;
    int nb_e  = (int)((E + 255) / 256);
    int nb_s  = (N + SCAN_TILE - 1) / SCAN_TILE;
    int nb_x  = (N * 32 + 255) / 256;
    int NBH   = (N + 7) / 8;           // agg blocks per feature-half

    bool fast = (N < 65536);   // packed (src<<16|dst), nbuck<=MAXBUCK

    if (fast) {
        hipMemsetAsync(btot_raw, 0, (size_t)nbuck * 4, stream);
        k_count    <<<nsb + 128, 256, 0, stream>>>(ei, W1, w1t, btot_raw, E, nbuck, nsb);
        k_btot_scan<<<1, 256, 0, stream>>>(btot_raw, btot, curg, nbuck);
        k_partition<<<nsb, 256, 0, stream>>>(ei, curg, part, E, nbuck);
        k_build_csr<<<nbuck, 256, 0, stream>>>(part, btot, x, rs, dis, csr_src,
                                               xs_lo, xs_hi, nbuck, N, E);
        k_agg_split<<<2 * NBH, 256, 0, stream>>>(xs_lo, xs_hi, csr_src, rs, dis,
                                                 aggh, N, NBH);
        k_mm       <<<(N + 63) / 64, 256, 0, stream>>>(aggh, w1t, b1, W2, dis, svs, N);
        k_out      <<<(N + 3) / 4, 256, 0, stream>>>(svs, csr_src, rs, dis, b2, out, N);
    } else {
        k_init        <<<nb_n, 256, 0, stream>>>(ei, flag, cnt, N);
        k_prep_w      <<<256, 128, 0, stream>>>(W1, w1t);
        k_count_slow  <<<nb_e, 256, 0, stream>>>(ei, flag, cnt, (int*)part, E);
        k_scan_partial<<<nb_s, 256, 0, stream>>>(cnt, bsum, N);
        k_scan_tops   <<<1, 64, 0, stream>>>(bsum, nb_s);
        k_scan_apply  <<<nb_s, 256, 0, stream>>>(cnt, bsum, rs, dis, N);
        k_prep_xs     <<<nb_x, 256, 0, stream>>>(x, dis, xs_lo, xs_hi, N);
        k_scatter_slow<<<nb_e, 256, 0, stream>>>(ei, flag, rs, (const int*)part, csr_src, E);
        k_agg_split   <<<2 * NBH, 256, 0, stream>>>(xs_lo, xs_hi, csr_src, rs, dis,
                                                    aggh, N, NBH);
        k_mm          <<<(N + 63) / 64, 256, 0, stream>>>(aggh, w1t, b1, W2, dis, svs, N);
        k_out         <<<(N + 3) / 4, 256, 0, stream>>>(svs, csr_src, rs, dis, b2, out, N);
    }
}